// Round 3
// baseline (2833.973 us; speedup 1.0000x reference)
//
#include <hip/hip_runtime.h>
#include <stdint.h>

#define NTRAIN 100000
#define BATCH  2048
#define DIM    64
#define KNN    128
#define CAP    3072      // candidate capacity per row
#define NSAMP  2048      // sampled points for threshold estimate
#define KSAMP  24        // take 24th smallest of sample as threshold
#define BM     32        // rows per distance block
#define TNS    256       // training points per tile
#define NCHUNK 8
#define CHUNK  12500

// workspace layout (bytes); total ~52.4 MB
#define OFF_THR   (0)
#define OFF_CNT   (64*1024)
#define OFF_SEL   (128*1024)
#define OFF_CAND  (2*1024*1024)   // 2048*3072*8 ; front 16.8MB doubles as sampleV (used before cand)

// ---------------- sample-distance kernel: v = |t|^2 - 2 x.t for 2048 strided samples ----------------
__global__ __launch_bounds__(256) void ksample(const float* __restrict__ x,
                                               const float* __restrict__ tX,
                                               float* __restrict__ sampleV)
{
    __shared__ float xsT[DIM][36];
    __shared__ float tT[DIM][TNS + 4];
    __shared__ float tns[TNS];
    const int tid = threadIdx.x;
    const int rb  = blockIdx.x * BM;

    { // stage x rows transposed: thread -> (row = tid&31, 8 dims)
        int r = tid & 31, d0 = (tid >> 5) * 8;
        const float4* xp = (const float4*)(x + (size_t)(rb + r) * DIM + d0);
        float4 v0 = xp[0], v1 = xp[1];
        xsT[d0+0][r]=v0.x; xsT[d0+1][r]=v0.y; xsT[d0+2][r]=v0.z; xsT[d0+3][r]=v0.w;
        xsT[d0+4][r]=v1.x; xsT[d0+5][r]=v1.y; xsT[d0+6][r]=v1.z; xsT[d0+7][r]=v1.w;
    }
    const int a = tid >> 5;   // row group (4 rows)
    const int b = tid & 31;   // col group (8 pts)

    for (int t0 = 0; t0 < NSAMP; t0 += TNS) {
        __syncthreads();
        { // stage one sampled point per thread (transposed) + its norm
            int s = t0 + tid;
            int p = (int)(((long long)s * NTRAIN) >> 11);
            const float4* tp = (const float4*)(tX + (size_t)p * DIM);
            float nrm = 0.f;
            #pragma unroll
            for (int q = 0; q < 16; ++q) {
                float4 v = tp[q];
                int d = q * 4;
                tT[d+0][tid]=v.x; tT[d+1][tid]=v.y; tT[d+2][tid]=v.z; tT[d+3][tid]=v.w;
                nrm = fmaf(v.x,v.x,nrm); nrm = fmaf(v.y,v.y,nrm);
                nrm = fmaf(v.z,v.z,nrm); nrm = fmaf(v.w,v.w,nrm);
            }
            tns[tid] = nrm;
        }
        __syncthreads();

        float acc[4][8];
        #pragma unroll
        for (int r=0;r<4;++r)
            #pragma unroll
            for (int c=0;c<8;++c) acc[r][c]=0.f;

        #pragma unroll 4
        for (int d = 0; d < DIM; ++d) {
            float4 xv  = *(const float4*)&xsT[d][a*4];
            float4 t0v = *(const float4*)&tT[d][b*8];
            float4 t1v = *(const float4*)&tT[d][b*8+4];
            float xr[4] = {xv.x,xv.y,xv.z,xv.w};
            float tv[8] = {t0v.x,t0v.y,t0v.z,t0v.w,t1v.x,t1v.y,t1v.z,t1v.w};
            #pragma unroll
            for (int r=0;r<4;++r)
                #pragma unroll
                for (int c=0;c<8;++c) acc[r][c] = fmaf(xr[r], tv[c], acc[r][c]);
        }
        #pragma unroll
        for (int r=0;r<4;++r) {
            int row = rb + a*4 + r;
            float4 o0, o1;
            o0.x = tns[b*8+0] - 2.f*acc[r][0]; o0.y = tns[b*8+1] - 2.f*acc[r][1];
            o0.z = tns[b*8+2] - 2.f*acc[r][2]; o0.w = tns[b*8+3] - 2.f*acc[r][3];
            o1.x = tns[b*8+4] - 2.f*acc[r][4]; o1.y = tns[b*8+5] - 2.f*acc[r][5];
            o1.z = tns[b*8+6] - 2.f*acc[r][6]; o1.w = tns[b*8+7] - 2.f*acc[r][7];
            *(float4*)&sampleV[(size_t)row * NSAMP + t0 + b*8]     = o0;
            *(float4*)&sampleV[(size_t)row * NSAMP + t0 + b*8 + 4] = o1;
        }
    }
}

// ---------------- per-row threshold: 24th smallest sample value ----------------
__global__ __launch_bounds__(256) void kthresh(const float* __restrict__ sampleV,
                                               float* __restrict__ thrv)
{
    __shared__ float sv[NSAMP];
    __shared__ float red[8];
    const int row = blockIdx.x, tid = threadIdx.x;
    for (int s = tid; s < NSAMP; s += 256) sv[s] = sampleV[(size_t)row * NSAMP + s];
    __syncthreads();
    float lb = -1e30f;
    for (int it = 0; it < KSAMP; ++it) {
        float m = 1e30f;
        for (int s = tid; s < NSAMP; s += 256) {
            float v = sv[s];
            m = (v > lb && v < m) ? v : m;
        }
        #pragma unroll
        for (int o = 1; o < 64; o <<= 1) m = fminf(m, __shfl_xor(m, o));
        if ((tid & 63) == 0) red[tid >> 6] = m;
        __syncthreads();
        lb = fminf(fminf(red[0], red[1]), fminf(red[2], red[3]));
        __syncthreads();
    }
    if (tid == 0) thrv[row] = lb;
}

// ---------------- main distance pass: append candidates v <= thr ----------------
__global__ __launch_bounds__(256) void kdist(const float* __restrict__ x,
                                             const float* __restrict__ tX,
                                             const float* __restrict__ thrv,
                                             unsigned int* __restrict__ gcnt,
                                             uint2* __restrict__ cand)
{
    __shared__ float xsT[DIM][36];
    __shared__ float tT[DIM][TNS + 4];
    __shared__ float tns[TNS];
    __shared__ float thr_s[BM];
    const int tid = threadIdx.x;
    const int rb  = (blockIdx.x & 63) * BM;
    const int ch  = blockIdx.x >> 6;
    const int p0c = ch * CHUNK;
    const int p1c = (p0c + CHUNK < NTRAIN) ? p0c + CHUNK : NTRAIN;

    {
        int r = tid & 31, d0 = (tid >> 5) * 8;
        const float4* xp = (const float4*)(x + (size_t)(rb + r) * DIM + d0);
        float4 v0 = xp[0], v1 = xp[1];
        xsT[d0+0][r]=v0.x; xsT[d0+1][r]=v0.y; xsT[d0+2][r]=v0.z; xsT[d0+3][r]=v0.w;
        xsT[d0+4][r]=v1.x; xsT[d0+5][r]=v1.y; xsT[d0+6][r]=v1.z; xsT[d0+7][r]=v1.w;
    }
    if (tid < BM) thr_s[tid] = thrv[rb + tid];

    const int a = tid >> 5, b = tid & 31;

    for (int t0 = p0c; t0 < p1c; t0 += TNS) {
        __syncthreads();
        {
            int p  = t0 + tid;
            int ok = (p < p1c);
            int pc = ok ? p : p0c;
            const float4* tp = (const float4*)(tX + (size_t)pc * DIM);
            float nrm = 0.f;
            #pragma unroll
            for (int q = 0; q < 16; ++q) {
                float4 v = tp[q];
                int d = q * 4;
                tT[d+0][tid]=v.x; tT[d+1][tid]=v.y; tT[d+2][tid]=v.z; tT[d+3][tid]=v.w;
                nrm = fmaf(v.x,v.x,nrm); nrm = fmaf(v.y,v.y,nrm);
                nrm = fmaf(v.z,v.z,nrm); nrm = fmaf(v.w,v.w,nrm);
            }
            tns[tid] = ok ? nrm : 1e30f;   // padded tail never passes threshold
        }
        __syncthreads();

        float acc[4][8];
        #pragma unroll
        for (int r=0;r<4;++r)
            #pragma unroll
            for (int c=0;c<8;++c) acc[r][c]=0.f;

        #pragma unroll 4
        for (int d = 0; d < DIM; ++d) {
            float4 xv  = *(const float4*)&xsT[d][a*4];
            float4 t0v = *(const float4*)&tT[d][b*8];
            float4 t1v = *(const float4*)&tT[d][b*8+4];
            float xr[4] = {xv.x,xv.y,xv.z,xv.w};
            float tv[8] = {t0v.x,t0v.y,t0v.z,t0v.w,t1v.x,t1v.y,t1v.z,t1v.w};
            #pragma unroll
            for (int r=0;r<4;++r)
                #pragma unroll
                for (int c=0;c<8;++c) acc[r][c] = fmaf(xr[r], tv[c], acc[r][c]);
        }
        #pragma unroll
        for (int r=0;r<4;++r) {
            const int row = rb + a*4 + r;
            const float th = thr_s[a*4 + r];
            #pragma unroll
            for (int c=0;c<8;++c) {
                float v = tns[b*8+c] - 2.f*acc[r][c];
                if (v <= th) {
                    unsigned pos = atomicAdd(&gcnt[row], 1u);
                    if (pos < CAP) {
                        unsigned bb  = __float_as_uint(v);
                        unsigned key = (bb >> 31) ? ~bb : (bb | 0x80000000u); // order-preserving map
                        cand[(size_t)row * CAP + pos] = make_uint2(key, (unsigned)(t0 + b*8 + c));
                    }
                }
            }
        }
    }
}

// ---------------- exact top-128 from candidates (binary search on key bits) ----------------
__global__ __launch_bounds__(256) void kselect(const unsigned int* __restrict__ gcnt,
                                               const uint2* __restrict__ cand,
                                               int* __restrict__ selIdx)
{
    __shared__ unsigned ku[CAP];
    __shared__ unsigned kid[CAP];
    __shared__ int redc[8];
    __shared__ int nsel;
    __shared__ int neq;
    __shared__ unsigned eqbuf[64];
    const int row = blockIdx.x, tid = threadIdx.x;
    int n = (int)gcnt[row]; if (n > CAP) n = CAP;
    for (int i = tid; i < n; i += 256) {
        uint2 e = cand[(size_t)row * CAP + i];
        ku[i] = e.x; kid[i] = e.y;
    }
    if (tid == 0) { nsel = 0; neq = 0; }
    __syncthreads();

    unsigned lo = 0u, hi = 0xFFFFFFFFu;
    for (int it = 0; it < 32; ++it) {
        unsigned mid = (unsigned)(((unsigned long long)lo + (unsigned long long)hi) >> 1);
        int c = 0;
        for (int i = tid; i < n; i += 256) c += (ku[i] <= mid) ? 1 : 0;
        #pragma unroll
        for (int o = 1; o < 64; o <<= 1) c += __shfl_xor(c, o);
        if ((tid & 63) == 0) redc[tid >> 6] = c;
        __syncthreads();
        int tot = redc[0] + redc[1] + redc[2] + redc[3];
        __syncthreads();
        if (tot >= KNN) hi = mid; else lo = mid + 1;
    }
    const unsigned ustar = hi;

    for (int i = tid; i < n; i += 256) {
        if (ku[i] < ustar) {
            int p = atomicAdd(&nsel, 1);
            if (p < KNN) selIdx[row * KNN + p] = (int)kid[i];
        } else if (ku[i] == ustar) {
            int p = atomicAdd(&neq, 1);
            if (p < 64) eqbuf[p] = kid[i];
        }
    }
    __syncthreads();
    if (tid == 0) {
        int cl = nsel; if (cl > KNN) cl = KNN;
        int need = KNN - cl;
        int ne = neq; if (ne > 64) ne = 64;
        // lowest-index tie-break to match lax.top_k stability
        for (int t = 0; t < need && t < ne; ++t) {
            int bi = t;
            for (int u = t + 1; u < ne; ++u) if (eqbuf[u] < eqbuf[bi]) bi = u;
            unsigned tmp = eqbuf[t]; eqbuf[t] = eqbuf[bi]; eqbuf[bi] = tmp;
            selIdx[row * KNN + cl + t] = (int)eqbuf[t];
        }
        int have = cl + (need < ne ? need : ne);
        for (int k2 = have; k2 < KNN; ++k2) selIdx[row * KNN + k2] = k2; // degenerate fallback
    }
}

// ---------------- per-row GP solve: register-resident symmetric forward elim + backsub ----------------
// Thread (c = tid&127, h = tid>>7) owns rows [64h,64h+64) of column c in registers r[64].
// Symmetry => pivot row == pivot column, owned by thread c==j, broadcast via 512B LDS prow
// (double-buffered: one barrier per pivot). After elim, U dumped into A buffer for parallel backsub.
__global__ __launch_bounds__(256) void ksolve2(const float* __restrict__ x,
                                               const float* __restrict__ tX,
                                               const float* __restrict__ ty,
                                               const int* __restrict__ selIdx,
                                               const float* __restrict__ pl,
                                               const float* __restrict__ pa,
                                               float* __restrict__ out)
{
    __shared__ float A[KNN][132];      // Gram/kernel matrix, later reused as U (row-major)
    __shared__ float nXTc[16][132];    // 16-dim transposed staging chunk
    __shared__ float prowb[2][KNN];    // double-buffered pivot row
    __shared__ float diag[KNN];
    __shared__ float rcpd[KNN];
    __shared__ float rhs[KNN];
    __shared__ float wv[KNN];
    __shared__ float c0v[KNN];
    __shared__ float nyv[KNN];
    __shared__ float nrmL[KNN];
    __shared__ float xq16[16];
    __shared__ int   sel[KNN];
    __shared__ float red[8];

    const int tid = threadIdx.x;
    const int row = blockIdx.x;
    const float ll = pl[0], aamp = pa[0];
    const float in2 = 1.0f / (2.0f * ll * ll);

    const int c = tid & 127;       // column owned
    const int h = tid >> 7;        // row half
    const int ta = tid >> 4, tb = tid & 15;
    const int i0 = ta * 8, j0 = tb * 8;

    if (tid < KNN) sel[tid] = selIdx[row * KNN + tid];
    __syncthreads();

    // ---- build: Gram via 8x8 register tiles over 4 dim-chunks of 16 ----
    float g[8][8];
    #pragma unroll
    for (int r2 = 0; r2 < 8; ++r2)
        #pragma unroll
        for (int c2 = 0; c2 < 8; ++c2) g[r2][c2] = 0.f;
    float xdot = 0.f, nacc = 0.f, xn = 0.f;

    for (int chk = 0; chk < 4; ++chk) {
        const int D0 = chk * 16;
        { // stage chunk transposed: thread (c,h) loads dims [D0+8h, D0+8h+8) of point c
            const float4* tp = (const float4*)(tX + (size_t)sel[c] * DIM + D0 + 8 * h);
            float4 v0 = tp[0], v1 = tp[1];
            int dd = 8 * h;
            nXTc[dd+0][c]=v0.x; nXTc[dd+1][c]=v0.y; nXTc[dd+2][c]=v0.z; nXTc[dd+3][c]=v0.w;
            nXTc[dd+4][c]=v1.x; nXTc[dd+5][c]=v1.y; nXTc[dd+6][c]=v1.z; nXTc[dd+7][c]=v1.w;
        }
        if (tid < 16) xq16[tid] = x[(size_t)row * DIM + D0 + tid];
        __syncthreads();

        for (int d = 0; d < 16; ++d) {
            float4 a0 = *(const float4*)&nXTc[d][i0];
            float4 a1 = *(const float4*)&nXTc[d][i0+4];
            float4 b0 = *(const float4*)&nXTc[d][j0];
            float4 b1 = *(const float4*)&nXTc[d][j0+4];
            float av[8] = {a0.x,a0.y,a0.z,a0.w,a1.x,a1.y,a1.z,a1.w};
            float bv[8] = {b0.x,b0.y,b0.z,b0.w,b1.x,b1.y,b1.z,b1.w};
            #pragma unroll
            for (int r2 = 0; r2 < 8; ++r2)
                #pragma unroll
                for (int c2 = 0; c2 < 8; ++c2) g[r2][c2] = fmaf(av[r2], bv[c2], g[r2][c2]);
        }
        if (tid < KNN) { // norms + cross-cov partials
            for (int d = 0; d < 16; ++d) {
                float t = nXTc[d][tid];
                float xv = xq16[d];
                nacc = fmaf(t, t, nacc);
                xdot = fmaf(xv, t, xdot);
                xn   = fmaf(xv, xv, xn);
            }
        }
        __syncthreads();   // before restaging next chunk
    }

    if (tid < KNN) {
        nrmL[tid] = nacc;
        float d2 = fmaxf(xn + nacc - 2.f * xdot, 0.f);
        float cv = aamp * __expf(-d2 * in2);
        c0v[tid] = cv;
        rhs[tid] = cv;
        nyv[tid] = ty[sel[tid]];
    }
    __syncthreads();

    // transform Gram -> kernel matrix A
    #pragma unroll
    for (int r2 = 0; r2 < 8; ++r2) {
        const float ni = nrmL[i0 + r2];
        float tmp[8];
        #pragma unroll
        for (int c2 = 0; c2 < 8; ++c2) {
            float d2 = fmaxf(ni + nrmL[j0 + c2] - 2.f * g[r2][c2], 0.f);
            tmp[c2] = aamp * __expf(-d2 * in2);
        }
        *(float4*)&A[i0+r2][j0]   = make_float4(tmp[0], tmp[1], tmp[2], tmp[3]);
        *(float4*)&A[i0+r2][j0+4] = make_float4(tmp[4], tmp[5], tmp[6], tmp[7]);
    }
    __syncthreads();

    // ---- load column halves into registers ----
    float r[64];
    #pragma unroll
    for (int il = 0; il < 64; ++il) r[il] = A[64 * h + il][c];

    if (c == 0) {  // seed pivot buffer 0 with column 0
        #pragma unroll
        for (int q = 0; q < 16; ++q)
            *(float4*)&prowb[0][64*h + 4*q] = make_float4(r[4*q], r[4*q+1], r[4*q+2], r[4*q+3]);
    }
    __syncthreads();

    // ---- forward elimination: one barrier per pivot (double-buffered prow) ----
    for (int j = 0; j < KNN; ++j) {
        const int buf = j & 1;
        const float pj = prowb[buf][j];
        const float rj = rhs[j];
        if (tid == 0) diag[j] = pj;
        if (c > j) {
            const float gg = prowb[buf][c] / pj;     // = f_c by symmetry
            if (h == 0) rhs[c] -= gg * rj;
            #pragma unroll
            for (int q = 0; q < 16; ++q) {
                const int ii0 = 64 * h + 4 * q;
                if (ii0 + 3 > j) {                   // wave-uniform chunk skip
                    float4 pv = *(const float4*)&prowb[buf][ii0];
                    if (ii0 + 0 > j) r[4*q+0] = fmaf(-gg, pv.x, r[4*q+0]);
                    if (ii0 + 1 > j) r[4*q+1] = fmaf(-gg, pv.y, r[4*q+1]);
                    if (ii0 + 2 > j) r[4*q+2] = fmaf(-gg, pv.z, r[4*q+2]);
                    if (ii0 + 3 > j) r[4*q+3] = fmaf(-gg, pv.w, r[4*q+3]);
                }
            }
            if (c == j + 1) {  // next pivot broadcasts its freshly-updated column
                #pragma unroll
                for (int q = 0; q < 16; ++q)
                    *(float4*)&prowb[buf ^ 1][64*h + 4*q] =
                        make_float4(r[4*q], r[4*q+1], r[4*q+2], r[4*q+3]);
            }
        }
        __syncthreads();
    }

    // ---- dump U into A buffer; reciprocal diag ----
    #pragma unroll
    for (int il = 0; il < 64; ++il) A[64 * h + il][c] = r[il];
    if (tid < KNN) rcpd[tid] = 1.0f / diag[tid];
    __syncthreads();

    // ---- backsubstitution: U w = rhs ----
    for (int j = KNN - 1; j >= 0; --j) {
        const float wj = rhs[j] * rcpd[j];
        if (h == 0) {
            if (c < j)       rhs[c] -= A[c][j] * wj;   // U[c][j]
            else if (c == j) wv[j] = wj;
        }
        __syncthreads();
    }

    // ---- outputs ----
    float py = 0.f, pq = 0.f;
    if (tid < KNN) {
        float w = wv[tid];
        py = w * nyv[tid];
        pq = w * c0v[tid];
    }
    #pragma unroll
    for (int o = 1; o < 64; o <<= 1) { py += __shfl_xor(py, o); pq += __shfl_xor(pq, o); }
    if ((tid & 63) == 0) { red[tid >> 6] = py; red[4 + (tid >> 6)] = pq; }
    __syncthreads();
    if (tid == 0) {
        float y = red[0] + red[1] + red[2] + red[3];
        float q = red[4] + red[5] + red[6] + red[7];
        out[row]         = y;
        out[BATCH + row] = aamp - q;
    }
}

extern "C" void kernel_launch(void* const* d_in, const int* in_sizes, int n_in,
                              void* d_out, int out_size, void* d_ws, size_t ws_size,
                              hipStream_t stream)
{
    const float* x  = (const float*)d_in[0];
    const float* tX = (const float*)d_in[1];
    const float* ty = (const float*)d_in[2];
    const float* pl = (const float*)d_in[3];
    const float* pa = (const float*)d_in[4];
    float* out = (float*)d_out;
    char* ws = (char*)d_ws;

    float*        thrv    = (float*)(ws + OFF_THR);
    unsigned int* gcnt    = (unsigned int*)(ws + OFF_CNT);
    int*          sel     = (int*)(ws + OFF_SEL);
    uint2*        cand    = (uint2*)(ws + OFF_CAND);
    float*        sampleV = (float*)(ws + OFF_CAND);  // aliased: consumed before cand is written

    hipMemsetAsync(gcnt, 0, BATCH * sizeof(unsigned int), stream);
    ksample<<<BATCH / BM, 256, 0, stream>>>(x, tX, sampleV);
    kthresh<<<BATCH, 256, 0, stream>>>(sampleV, thrv);
    kdist<<<(BATCH / BM) * NCHUNK, 256, 0, stream>>>(x, tX, thrv, gcnt, cand);
    kselect<<<BATCH, 256, 0, stream>>>(gcnt, cand, sel);
    ksolve2<<<BATCH, 256, 0, stream>>>(x, tX, ty, sel, pl, pa, out);
}

// Round 4
// 1571.327 us; speedup vs baseline: 1.8036x; 1.8036x over previous
//
#include <hip/hip_runtime.h>
#include <stdint.h>

#define NTRAIN 100000
#define BATCH  2048
#define DIM    64
#define KNN    128
#define CAP    3072      // candidate capacity per row
#define NSAMP  2048      // sampled points for threshold estimate
#define KSAMP  24        // take 24th smallest of sample as threshold
#define BM     32        // rows per distance block
#define TNS    256       // training points per tile
#define NCHUNK 8
#define CHUNK  12500

// workspace layout (bytes); total ~52.4 MB
#define OFF_THR   (0)
#define OFF_CNT   (64*1024)
#define OFF_SEL   (128*1024)
#define OFF_CAND  (2*1024*1024)   // 2048*3072*8 ; front 16.8MB doubles as sampleV (used before cand)

// ---------------- sample-distance kernel: v = |t|^2 - 2 x.t for 2048 strided samples ----------------
__global__ __launch_bounds__(256) void ksample(const float* __restrict__ x,
                                               const float* __restrict__ tX,
                                               float* __restrict__ sampleV)
{
    __shared__ float xsT[DIM][36];
    __shared__ float tT[DIM][TNS + 4];
    __shared__ float tns[TNS];
    const int tid = threadIdx.x;
    const int rb  = blockIdx.x * BM;

    { // stage x rows transposed: thread -> (row = tid&31, 8 dims)
        int r = tid & 31, d0 = (tid >> 5) * 8;
        const float4* xp = (const float4*)(x + (size_t)(rb + r) * DIM + d0);
        float4 v0 = xp[0], v1 = xp[1];
        xsT[d0+0][r]=v0.x; xsT[d0+1][r]=v0.y; xsT[d0+2][r]=v0.z; xsT[d0+3][r]=v0.w;
        xsT[d0+4][r]=v1.x; xsT[d0+5][r]=v1.y; xsT[d0+6][r]=v1.z; xsT[d0+7][r]=v1.w;
    }
    const int a = tid >> 5;   // row group (4 rows)
    const int b = tid & 31;   // col group (8 pts)

    for (int t0 = 0; t0 < NSAMP; t0 += TNS) {
        __syncthreads();
        { // stage one sampled point per thread (transposed) + its norm
            int s = t0 + tid;
            int p = (int)(((long long)s * NTRAIN) >> 11);
            const float4* tp = (const float4*)(tX + (size_t)p * DIM);
            float nrm = 0.f;
            #pragma unroll
            for (int q = 0; q < 16; ++q) {
                float4 v = tp[q];
                int d = q * 4;
                tT[d+0][tid]=v.x; tT[d+1][tid]=v.y; tT[d+2][tid]=v.z; tT[d+3][tid]=v.w;
                nrm = fmaf(v.x,v.x,nrm); nrm = fmaf(v.y,v.y,nrm);
                nrm = fmaf(v.z,v.z,nrm); nrm = fmaf(v.w,v.w,nrm);
            }
            tns[tid] = nrm;
        }
        __syncthreads();

        float acc[4][8];
        #pragma unroll
        for (int r=0;r<4;++r)
            #pragma unroll
            for (int c=0;c<8;++c) acc[r][c]=0.f;

        #pragma unroll 4
        for (int d = 0; d < DIM; ++d) {
            float4 xv  = *(const float4*)&xsT[d][a*4];
            float4 t0v = *(const float4*)&tT[d][b*8];
            float4 t1v = *(const float4*)&tT[d][b*8+4];
            float xr[4] = {xv.x,xv.y,xv.z,xv.w};
            float tv[8] = {t0v.x,t0v.y,t0v.z,t0v.w,t1v.x,t1v.y,t1v.z,t1v.w};
            #pragma unroll
            for (int r=0;r<4;++r)
                #pragma unroll
                for (int c=0;c<8;++c) acc[r][c] = fmaf(xr[r], tv[c], acc[r][c]);
        }
        #pragma unroll
        for (int r=0;r<4;++r) {
            int row = rb + a*4 + r;
            float4 o0, o1;
            o0.x = tns[b*8+0] - 2.f*acc[r][0]; o0.y = tns[b*8+1] - 2.f*acc[r][1];
            o0.z = tns[b*8+2] - 2.f*acc[r][2]; o0.w = tns[b*8+3] - 2.f*acc[r][3];
            o1.x = tns[b*8+4] - 2.f*acc[r][4]; o1.y = tns[b*8+5] - 2.f*acc[r][5];
            o1.z = tns[b*8+6] - 2.f*acc[r][6]; o1.w = tns[b*8+7] - 2.f*acc[r][7];
            *(float4*)&sampleV[(size_t)row * NSAMP + t0 + b*8]     = o0;
            *(float4*)&sampleV[(size_t)row * NSAMP + t0 + b*8 + 4] = o1;
        }
    }
}

// ---------------- per-row threshold: 24th smallest sample value ----------------
__global__ __launch_bounds__(256) void kthresh(const float* __restrict__ sampleV,
                                               float* __restrict__ thrv)
{
    __shared__ float sv[NSAMP];
    __shared__ float red[8];
    const int row = blockIdx.x, tid = threadIdx.x;
    for (int s = tid; s < NSAMP; s += 256) sv[s] = sampleV[(size_t)row * NSAMP + s];
    __syncthreads();
    float lb = -1e30f;
    for (int it = 0; it < KSAMP; ++it) {
        float m = 1e30f;
        for (int s = tid; s < NSAMP; s += 256) {
            float v = sv[s];
            m = (v > lb && v < m) ? v : m;
        }
        #pragma unroll
        for (int o = 1; o < 64; o <<= 1) m = fminf(m, __shfl_xor(m, o));
        if ((tid & 63) == 0) red[tid >> 6] = m;
        __syncthreads();
        lb = fminf(fminf(red[0], red[1]), fminf(red[2], red[3]));
        __syncthreads();
    }
    if (tid == 0) thrv[row] = lb;
}

// ---------------- main distance pass: append candidates v <= thr ----------------
__global__ __launch_bounds__(256) void kdist(const float* __restrict__ x,
                                             const float* __restrict__ tX,
                                             const float* __restrict__ thrv,
                                             unsigned int* __restrict__ gcnt,
                                             uint2* __restrict__ cand)
{
    __shared__ float xsT[DIM][36];
    __shared__ float tT[DIM][TNS + 4];
    __shared__ float tns[TNS];
    __shared__ float thr_s[BM];
    const int tid = threadIdx.x;
    const int rb  = (blockIdx.x & 63) * BM;
    const int ch  = blockIdx.x >> 6;
    const int p0c = ch * CHUNK;
    const int p1c = (p0c + CHUNK < NTRAIN) ? p0c + CHUNK : NTRAIN;

    {
        int r = tid & 31, d0 = (tid >> 5) * 8;
        const float4* xp = (const float4*)(x + (size_t)(rb + r) * DIM + d0);
        float4 v0 = xp[0], v1 = xp[1];
        xsT[d0+0][r]=v0.x; xsT[d0+1][r]=v0.y; xsT[d0+2][r]=v0.z; xsT[d0+3][r]=v0.w;
        xsT[d0+4][r]=v1.x; xsT[d0+5][r]=v1.y; xsT[d0+6][r]=v1.z; xsT[d0+7][r]=v1.w;
    }
    if (tid < BM) thr_s[tid] = thrv[rb + tid];

    const int a = tid >> 5, b = tid & 31;

    for (int t0 = p0c; t0 < p1c; t0 += TNS) {
        __syncthreads();
        {
            int p  = t0 + tid;
            int ok = (p < p1c);
            int pc = ok ? p : p0c;
            const float4* tp = (const float4*)(tX + (size_t)pc * DIM);
            float nrm = 0.f;
            #pragma unroll
            for (int q = 0; q < 16; ++q) {
                float4 v = tp[q];
                int d = q * 4;
                tT[d+0][tid]=v.x; tT[d+1][tid]=v.y; tT[d+2][tid]=v.z; tT[d+3][tid]=v.w;
                nrm = fmaf(v.x,v.x,nrm); nrm = fmaf(v.y,v.y,nrm);
                nrm = fmaf(v.z,v.z,nrm); nrm = fmaf(v.w,v.w,nrm);
            }
            tns[tid] = ok ? nrm : 1e30f;   // padded tail never passes threshold
        }
        __syncthreads();

        float acc[4][8];
        #pragma unroll
        for (int r=0;r<4;++r)
            #pragma unroll
            for (int c=0;c<8;++c) acc[r][c]=0.f;

        #pragma unroll 4
        for (int d = 0; d < DIM; ++d) {
            float4 xv  = *(const float4*)&xsT[d][a*4];
            float4 t0v = *(const float4*)&tT[d][b*8];
            float4 t1v = *(const float4*)&tT[d][b*8+4];
            float xr[4] = {xv.x,xv.y,xv.z,xv.w};
            float tv[8] = {t0v.x,t0v.y,t0v.z,t0v.w,t1v.x,t1v.y,t1v.z,t1v.w};
            #pragma unroll
            for (int r=0;r<4;++r)
                #pragma unroll
                for (int c=0;c<8;++c) acc[r][c] = fmaf(xr[r], tv[c], acc[r][c]);
        }
        #pragma unroll
        for (int r=0;r<4;++r) {
            const int row = rb + a*4 + r;
            const float th = thr_s[a*4 + r];
            #pragma unroll
            for (int c=0;c<8;++c) {
                float v = tns[b*8+c] - 2.f*acc[r][c];
                if (v <= th) {
                    unsigned pos = atomicAdd(&gcnt[row], 1u);
                    if (pos < CAP) {
                        unsigned bb  = __float_as_uint(v);
                        unsigned key = (bb >> 31) ? ~bb : (bb | 0x80000000u); // order-preserving map
                        cand[(size_t)row * CAP + pos] = make_uint2(key, (unsigned)(t0 + b*8 + c));
                    }
                }
            }
        }
    }
}

// ---------------- exact top-128 from candidates (binary search on key bits) ----------------
__global__ __launch_bounds__(256) void kselect(const unsigned int* __restrict__ gcnt,
                                               const uint2* __restrict__ cand,
                                               int* __restrict__ selIdx)
{
    __shared__ unsigned ku[CAP];
    __shared__ unsigned kid[CAP];
    __shared__ int redc[8];
    __shared__ int nsel;
    __shared__ int neq;
    __shared__ unsigned eqbuf[64];
    const int row = blockIdx.x, tid = threadIdx.x;
    int n = (int)gcnt[row]; if (n > CAP) n = CAP;
    for (int i = tid; i < n; i += 256) {
        uint2 e = cand[(size_t)row * CAP + i];
        ku[i] = e.x; kid[i] = e.y;
    }
    if (tid == 0) { nsel = 0; neq = 0; }
    __syncthreads();

    unsigned lo = 0u, hi = 0xFFFFFFFFu;
    for (int it = 0; it < 32; ++it) {
        unsigned mid = (unsigned)(((unsigned long long)lo + (unsigned long long)hi) >> 1);
        int c = 0;
        for (int i = tid; i < n; i += 256) c += (ku[i] <= mid) ? 1 : 0;
        #pragma unroll
        for (int o = 1; o < 64; o <<= 1) c += __shfl_xor(c, o);
        if ((tid & 63) == 0) redc[tid >> 6] = c;
        __syncthreads();
        int tot = redc[0] + redc[1] + redc[2] + redc[3];
        __syncthreads();
        if (tot >= KNN) hi = mid; else lo = mid + 1;
    }
    const unsigned ustar = hi;

    for (int i = tid; i < n; i += 256) {
        if (ku[i] < ustar) {
            int p = atomicAdd(&nsel, 1);
            if (p < KNN) selIdx[row * KNN + p] = (int)kid[i];
        } else if (ku[i] == ustar) {
            int p = atomicAdd(&neq, 1);
            if (p < 64) eqbuf[p] = kid[i];
        }
    }
    __syncthreads();
    if (tid == 0) {
        int cl = nsel; if (cl > KNN) cl = KNN;
        int need = KNN - cl;
        int ne = neq; if (ne > 64) ne = 64;
        // lowest-index tie-break to match lax.top_k stability
        for (int t = 0; t < need && t < ne; ++t) {
            int bi = t;
            for (int u = t + 1; u < ne; ++u) if (eqbuf[u] < eqbuf[bi]) bi = u;
            unsigned tmp = eqbuf[t]; eqbuf[t] = eqbuf[bi]; eqbuf[bi] = tmp;
            selIdx[row * KNN + cl + t] = (int)eqbuf[t];
        }
        int have = cl + (need < ne ? need : ne);
        for (int k2 = have; k2 < KNN; ++k2) selIdx[row * KNN + k2] = k2; // degenerate fallback
    }
}

// =================== ksolve3: blocked register-tile LU (panel=16), wave-factored panels ===========
// Thread (c=tid&127, h=tid>>7) owns rows [64h,64h+64) of column c in r[64] (static-indexed).
// Per panel: dump 16 cols -> LDS P; ONE WAVE factors the 128x16 panel in registers via __shfl
// (16 unrolled steps, rhs carried, no block barriers inside); then all threads apply the rank-16
// trailing update from broadcast LDS reads. Backsub: 16-lane shfl solve + parallel rank-16 updates.
// ~70 block barriers total vs ~260 per-pivot barriers in ksolve2.

#define PSTR 20                       // P row stride (floats): 80B, 16B-aligned
#define PIDX(row,col) ((row)*PSTR + (col))
#define UOFF 2560                     // Uc region offset in BUF (floats)

template<int LO>
__device__ __forceinline__ void dumpP(const float* r, float* BUF, int cB, int base) {
    #pragma unroll
    for (int i = LO; i < 64; ++i) BUF[PIDX(base + i, cB)] = r[i];
}

template<int LO>
__device__ __forceinline__ void loadP(float* r, const float* BUF, int cB, int base) {
    #pragma unroll
    for (int i = LO; i < 64; ++i) r[i] = BUF[PIDX(base + i, cB)];
}

template<int LO>
__device__ __forceinline__ void trail16(float* r, const float* u, const float* BUF, int base) {
    #pragma unroll
    for (int i = LO; i < 64; ++i) {
        const float* pr = &BUF[PIDX(base + i, 0)];
        float4 p0 = *(const float4*)(pr);
        float4 p1 = *(const float4*)(pr + 4);
        float4 p2 = *(const float4*)(pr + 8);
        float4 p3 = *(const float4*)(pr + 12);
        float s = r[i];
        s = fmaf(-p0.x, u[0],  s); s = fmaf(-p0.y, u[1],  s);
        s = fmaf(-p0.z, u[2],  s); s = fmaf(-p0.w, u[3],  s);
        s = fmaf(-p1.x, u[4],  s); s = fmaf(-p1.y, u[5],  s);
        s = fmaf(-p1.z, u[6],  s); s = fmaf(-p1.w, u[7],  s);
        s = fmaf(-p2.x, u[8],  s); s = fmaf(-p2.y, u[9],  s);
        s = fmaf(-p2.z, u[10], s); s = fmaf(-p2.w, u[11], s);
        s = fmaf(-p3.x, u[12], s); s = fmaf(-p3.y, u[13], s);
        s = fmaf(-p3.z, u[14], s); s = fmaf(-p3.w, u[15], s);
        r[i] = s;
    }
}

// h==hB trailing thread: triangular-update its 16 panel rows, publish U-seg, apply own trailing
template<int PO>
__device__ __forceinline__ void eqTrail(float* r, float* BUF, int jB, int base, int c) {
    #pragma unroll
    for (int a = 0; a < 15; ++a) {
        float va = r[PO + a];
        #pragma unroll
        for (int b = a + 1; b < 16; ++b)
            r[PO + b] = fmaf(-BUF[PIDX(jB + b, a)], va, r[PO + b]);
    }
    float u[16];
    #pragma unroll
    for (int jj = 0; jj < 16; ++jj) { u[jj] = r[PO + jj]; BUF[UOFF + c * PSTR + jj] = u[jj]; }
    trail16<PO + 16>(r, u, BUF, base);
}

template<int HI>
__device__ __forceinline__ void partW(const float* r, float* BUF, int base, int t, float wc) {
    #pragma unroll
    for (int i = 0; i < HI; ++i) BUF[UOFF + (base + i) * PSTR + t] = r[i] * wc;
}

template<int PO>
__device__ __forceinline__ void dumpDiag(const float* r, float* BUF, int cB) {
    #pragma unroll
    for (int rr = 0; rr < 16; ++rr) BUF[PIDX(rr, cB)] = r[PO + rr];
}

__global__ __launch_bounds__(256, 3) void ksolve3(const float* __restrict__ x,
                                                  const float* __restrict__ tX,
                                                  const float* __restrict__ ty,
                                                  const int* __restrict__ selIdx,
                                                  const float* __restrict__ pl,
                                                  const float* __restrict__ pa,
                                                  float* __restrict__ out)
{
    __shared__ float BUF[128 * 68];          // 34.8KB: XsR[c][d] (build) overlaid with P + Uc (solve)
    __shared__ float rhs[KNN], wv[KNN], c0v[KNN], nyv[KNN], nrmL[KNN];
    __shared__ float xq[DIM];
    __shared__ float nrm2f[2][KNN];
    __shared__ int   sel[KNN];
    __shared__ float red[8];

    const int tid = threadIdx.x;
    const int row = blockIdx.x;
    const int c = tid & 127;
    const int h = tid >> 7;
    const int base = 64 * h;
    const float ll = pl[0], aamp = pa[0];
    const float in2 = 1.0f / (2.0f * ll * ll);

    if (tid < KNN) sel[tid] = selIdx[row * KNN + tid];
    if (tid < DIM) xq[tid] = x[(size_t)row * DIM + tid];
    __syncthreads();

    // ---- stage neighbor rows (row-major) + partial norms ----
    {
        const float* tp = tX + (size_t)sel[c] * DIM + 32 * h;
        float pn = 0.f;
        #pragma unroll
        for (int q = 0; q < 8; ++q) {
            float4 v = *(const float4*)(tp + 4 * q);
            *(float4*)&BUF[c * 68 + 32 * h + 4 * q] = v;
            pn = fmaf(v.x, v.x, fmaf(v.y, v.y, fmaf(v.z, v.z, fmaf(v.w, v.w, pn))));
        }
        nrm2f[h][c] = pn;
        if (h == 0) nyv[c] = ty[sel[c]];
    }
    __syncthreads();

    // ---- per-column: norms + crossCov (rhs) ----
    if (h == 0) {
        float nn = nrm2f[0][c] + nrm2f[1][c];
        nrmL[c] = nn;
        float xd = 0.f, xn = 0.f;
        for (int d = 0; d < DIM; ++d) {
            float xv = xq[d];
            float t = BUF[c * 68 + d];
            xd = fmaf(xv, t, xd);
            xn = fmaf(xv, xv, xn);
        }
        float d2 = fmaxf(xn + nn - 2.f * xd, 0.f);
        float cv = aamp * __expf(-d2 * in2);
        c0v[c] = cv;
        rhs[c] = cv;
    }
    __syncthreads();

    // ---- Gram into registers ----
    float r[64];
    #pragma unroll
    for (int i = 0; i < 64; ++i) r[i] = 0.f;
    for (int q4 = 0; q4 < 4; ++q4) {
        float od[16];
        #pragma unroll
        for (int q = 0; q < 4; ++q)
            *(float4*)&od[4 * q] = *(const float4*)&BUF[c * 68 + 16 * q4 + 4 * q];
        #pragma unroll
        for (int i = 0; i < 64; ++i) {
            const float* br = &BUF[(base + i) * 68 + 16 * q4];
            float4 b0 = *(const float4*)(br);
            float4 b1 = *(const float4*)(br + 4);
            float4 b2 = *(const float4*)(br + 8);
            float4 b3 = *(const float4*)(br + 12);
            float s = r[i];
            s = fmaf(b0.x, od[0],  s); s = fmaf(b0.y, od[1],  s);
            s = fmaf(b0.z, od[2],  s); s = fmaf(b0.w, od[3],  s);
            s = fmaf(b1.x, od[4],  s); s = fmaf(b1.y, od[5],  s);
            s = fmaf(b1.z, od[6],  s); s = fmaf(b1.w, od[7],  s);
            s = fmaf(b2.x, od[8],  s); s = fmaf(b2.y, od[9],  s);
            s = fmaf(b2.z, od[10], s); s = fmaf(b2.w, od[11], s);
            s = fmaf(b3.x, od[12], s); s = fmaf(b3.y, od[13], s);
            s = fmaf(b3.z, od[14], s); s = fmaf(b3.w, od[15], s);
            r[i] = s;
        }
    }
    // ---- transform Gram -> kernel matrix (in registers) ----
    {
        const float ncl = nrmL[c];
        #pragma unroll
        for (int i = 0; i < 64; ++i) {
            float d2 = fmaxf(nrmL[base + i] + ncl - 2.f * r[i], 0.f);
            r[i] = aamp * __expf(-d2 * in2);
        }
    }
    __syncthreads();   // hand BUF over from XsR to P/Uc

    // ================= forward: blocked LU, 8 panels =================
    for (int kb = 0; kb < 8; ++kb) {
        const int jB = 16 * kb;
        const int po = jB - base;                 // panel offset in local row coords
        const bool inB = (c >= jB) && (c < jB + 16);
        const bool trC = (c > jB + 15);

        // --- A: dump panel columns to P ---
        if (inB) {
            const int cB = c - jB;
            if (po < 0)            dumpP<0>(r, BUF, cB, base);
            else if (po == 0)      dumpP<0>(r, BUF, cB, base);
            else if (po == 16)     dumpP<16>(r, BUF, cB, base);
            else if (po == 32)     dumpP<32>(r, BUF, cB, base);
            else if (po == 48)     dumpP<48>(r, BUF, cB, base);
        }
        __syncthreads();

        // --- B: wave 0 factors the 128x16 panel + rhs in registers via shfl ---
        if (tid < 64) {
            const int l = tid;
            const int ga = jB + l, gb = jB + 64 + l;
            const bool va = ga < 128, vb = gb < 128;
            float ra[16], rb[16], rha = 0.f, rhb = 0.f;
            if (va) {
                #pragma unroll
                for (int q = 0; q < 4; ++q) *(float4*)&ra[4*q] = *(const float4*)&BUF[PIDX(ga, 4*q)];
                rha = rhs[ga];
            }
            if (vb) {
                #pragma unroll
                for (int q = 0; q < 4; ++q) *(float4*)&rb[4*q] = *(const float4*)&BUF[PIDX(gb, 4*q)];
                rhb = rhs[gb];
            }
            #pragma unroll
            for (int jj = 0; jj < 16; ++jj) {
                float pv[16];
                #pragma unroll
                for (int q = 0; q < 16; ++q) pv[q] = __shfl(ra[q], jj);
                float pvr = __shfl(rha, jj);
                const float rc = 1.0f / pv[jj];
                if (va && l > jj) {
                    float m = ra[jj] * rc; ra[jj] = m;
                    #pragma unroll
                    for (int cc = jj + 1; cc < 16; ++cc) ra[cc] = fmaf(-m, pv[cc], ra[cc]);
                    rha = fmaf(-m, pvr, rha);
                }
                if (vb) {
                    float m = rb[jj] * rc; rb[jj] = m;
                    #pragma unroll
                    for (int cc = jj + 1; cc < 16; ++cc) rb[cc] = fmaf(-m, pv[cc], rb[cc]);
                    rhb = fmaf(-m, pvr, rhb);
                }
            }
            if (va) {
                #pragma unroll
                for (int q = 0; q < 4; ++q) *(float4*)&BUF[PIDX(ga, 4*q)] = *(const float4*)&ra[4*q];
                rhs[ga] = rha;
            }
            if (vb) {
                #pragma unroll
                for (int q = 0; q < 4; ++q) *(float4*)&BUF[PIDX(gb, 4*q)] = *(const float4*)&rb[4*q];
                rhs[gb] = rhb;
            }
        }
        __syncthreads();

        // --- C: readback for panel columns; h==hB trailing: tri-update + publish U-seg + own trail ---
        if (po >= 0 && po < 64) {                 // h == hB
            if (inB) {
                const int cB = c - jB;
                if (po == 0)       loadP<0>(r, BUF, cB, base);
                else if (po == 16) loadP<16>(r, BUF, cB, base);
                else if (po == 32) loadP<32>(r, BUF, cB, base);
                else               loadP<48>(r, BUF, cB, base);
            } else if (trC) {
                if (po == 0)       eqTrail<0>(r, BUF, jB, base, c);
                else if (po == 16) eqTrail<16>(r, BUF, jB, base, c);
                else if (po == 32) eqTrail<32>(r, BUF, jB, base, c);
                else               eqTrail<48>(r, BUF, jB, base, c);
            }
        } else if (po < 0) {                      // h > hB
            if (inB) loadP<0>(r, BUF, c - jB, base);
        }
        __syncthreads();

        // --- D: h>hB trailing threads apply rank-16 update with U-seg from Uc ---
        if (po < 0 && trC) {
            float u[16];
            #pragma unroll
            for (int q = 0; q < 4; ++q)
                *(float4*)&u[4*q] = *(const float4*)&BUF[UOFF + c * PSTR + 4*q];
            trail16<0>(r, u, BUF, base);
        }
        __syncthreads();
    }

    // ================= backsub: 8 blocks, top-down =================
    for (int kb = 7; kb >= 0; --kb) {
        const int jB = 16 * kb;
        const int po = jB - base;
        const bool inB = (c >= jB) && (c < jB + 16);

        // --- A: diag-block dump (h==hB, c in B) ---
        if (inB && po >= 0 && po < 64) {
            const int cB = c - jB;
            if (po == 0)       dumpDiag<0>(r, BUF, cB);
            else if (po == 16) dumpDiag<16>(r, BUF, cB);
            else if (po == 32) dumpDiag<32>(r, BUF, cB);
            else               dumpDiag<48>(r, BUF, cB);
        }
        __syncthreads();

        // --- B: 16-lane shfl solve of upper-triangular 16x16 ---
        if (tid < 16) {
            float rl = rhs[jB + tid];
            #pragma unroll
            for (int t = 15; t >= 0; --t) {
                float rj = __shfl(rl, t);
                float wj = rj / BUF[PIDX(t, t)];
                if (tid == t) wv[jB + t] = wj;
                if (tid < t) rl = fmaf(-BUF[PIDX(tid, t)], wj, rl);
            }
        }
        __syncthreads();

        if (kb > 0) {
            // --- C: partial products U[row][c]*w_c into Uc slots ---
            if (inB) {
                const float wc = wv[c];
                const int t = c - jB;
                if (po >= 64)      partW<64>(r, BUF, base, t, wc);   // h < hB: all 64 rows < jB
                else if (po == 16) partW<16>(r, BUF, base, t, wc);
                else if (po == 32) partW<32>(r, BUF, base, t, wc);
                else if (po == 48) partW<48>(r, BUF, base, t, wc);
                // po == 0: no rows above panel in this half
            }
            __syncthreads();
            // --- D: reduce 16 partials per row into rhs ---
            if (tid < jB) {
                const float* up = &BUF[UOFF + tid * PSTR];
                float4 v0 = *(const float4*)(up);
                float4 v1 = *(const float4*)(up + 4);
                float4 v2 = *(const float4*)(up + 8);
                float4 v3 = *(const float4*)(up + 12);
                float s = v0.x + v0.y + v0.z + v0.w + v1.x + v1.y + v1.z + v1.w
                        + v2.x + v2.y + v2.z + v2.w + v3.x + v3.y + v3.z + v3.w;
                rhs[tid] -= s;
            }
            __syncthreads();
        }
    }
    __syncthreads();

    // ---- outputs: y = w.ny ; yVar = a - w.c ----
    float py = 0.f, pq = 0.f;
    if (tid < KNN) {
        float w = wv[tid];
        py = w * nyv[tid];
        pq = w * c0v[tid];
    }
    #pragma unroll
    for (int o = 1; o < 64; o <<= 1) { py += __shfl_xor(py, o); pq += __shfl_xor(pq, o); }
    if ((tid & 63) == 0) { red[tid >> 6] = py; red[4 + (tid >> 6)] = pq; }
    __syncthreads();
    if (tid == 0) {
        float y = red[0] + red[1] + red[2] + red[3];
        float q = red[4] + red[5] + red[6] + red[7];
        out[row]         = y;
        out[BATCH + row] = aamp - q;
    }
}

extern "C" void kernel_launch(void* const* d_in, const int* in_sizes, int n_in,
                              void* d_out, int out_size, void* d_ws, size_t ws_size,
                              hipStream_t stream)
{
    const float* x  = (const float*)d_in[0];
    const float* tX = (const float*)d_in[1];
    const float* ty = (const float*)d_in[2];
    const float* pl = (const float*)d_in[3];
    const float* pa = (const float*)d_in[4];
    float* out = (float*)d_out;
    char* ws = (char*)d_ws;

    float*        thrv    = (float*)(ws + OFF_THR);
    unsigned int* gcnt    = (unsigned int*)(ws + OFF_CNT);
    int*          sel     = (int*)(ws + OFF_SEL);
    uint2*        cand    = (uint2*)(ws + OFF_CAND);
    float*        sampleV = (float*)(ws + OFF_CAND);  // aliased: consumed before cand is written

    hipMemsetAsync(gcnt, 0, BATCH * sizeof(unsigned int), stream);
    ksample<<<BATCH / BM, 256, 0, stream>>>(x, tX, sampleV);
    kthresh<<<BATCH, 256, 0, stream>>>(sampleV, thrv);
    kdist<<<(BATCH / BM) * NCHUNK, 256, 0, stream>>>(x, tX, thrv, gcnt, cand);
    kselect<<<BATCH, 256, 0, stream>>>(gcnt, cand, sel);
    ksolve3<<<BATCH, 256, 0, stream>>>(x, tX, ty, sel, pl, pa, out);
}

// Round 6
// 1199.211 us; speedup vs baseline: 2.3632x; 1.3103x over previous
//
#include <hip/hip_runtime.h>
#include <stdint.h>

#define NTRAIN 100000
#define BATCH  2048
#define DIM    64
#define KNN    128
#define CAP    3072      // candidate capacity per row
#define NSAMP  2048      // sampled points for threshold estimate
#define KSAMP  24        // take 24th smallest of sample as threshold
#define BM     32        // rows per distance block (ksample)
#define TNS    256       // training points per tile (ksample)

// kdist2 geometry
#define BM2    64        // rows per block
#define TN2    128       // points per tile
#define NCH2   24        // chunks -> grid 32*24=768 blocks (3/CU)
#define CH2    4167      // ceil(100000/24)
#define CBCAP  6         // LDS candidate buffer capacity per row per tile

// workspace layout (bytes); total ~52.4 MB
#define OFF_THR   (0)
#define OFF_CNT   (64*1024)
#define OFF_SEL   (128*1024)
#define OFF_CAND  (2*1024*1024)   // 2048*3072*8 ; front 16.8MB doubles as sampleV (used before cand)

// ---------------- sample-distance kernel: v = |t|^2 - 2 x.t for 2048 strided samples ----------------
__global__ __launch_bounds__(256) void ksample(const float* __restrict__ x,
                                               const float* __restrict__ tX,
                                               float* __restrict__ sampleV)
{
    __shared__ float xsT[DIM][36];
    __shared__ float tT[DIM][TNS + 4];
    __shared__ float tns[TNS];
    const int tid = threadIdx.x;
    const int rb  = blockIdx.x * BM;

    { // stage x rows transposed: thread -> (row = tid&31, 8 dims)
        int r = tid & 31, d0 = (tid >> 5) * 8;
        const float4* xp = (const float4*)(x + (size_t)(rb + r) * DIM + d0);
        float4 v0 = xp[0], v1 = xp[1];
        xsT[d0+0][r]=v0.x; xsT[d0+1][r]=v0.y; xsT[d0+2][r]=v0.z; xsT[d0+3][r]=v0.w;
        xsT[d0+4][r]=v1.x; xsT[d0+5][r]=v1.y; xsT[d0+6][r]=v1.z; xsT[d0+7][r]=v1.w;
    }
    const int a = tid >> 5;   // row group (4 rows)
    const int b = tid & 31;   // col group (8 pts)

    for (int t0 = 0; t0 < NSAMP; t0 += TNS) {
        __syncthreads();
        { // stage one sampled point per thread (transposed) + its norm
            int s = t0 + tid;
            int p = (int)(((long long)s * NTRAIN) >> 11);
            const float4* tp = (const float4*)(tX + (size_t)p * DIM);
            float nrm = 0.f;
            #pragma unroll
            for (int q = 0; q < 16; ++q) {
                float4 v = tp[q];
                int d = q * 4;
                tT[d+0][tid]=v.x; tT[d+1][tid]=v.y; tT[d+2][tid]=v.z; tT[d+3][tid]=v.w;
                nrm = fmaf(v.x,v.x,nrm); nrm = fmaf(v.y,v.y,nrm);
                nrm = fmaf(v.z,v.z,nrm); nrm = fmaf(v.w,v.w,nrm);
            }
            tns[tid] = nrm;
        }
        __syncthreads();

        float acc[4][8];
        #pragma unroll
        for (int r=0;r<4;++r)
            #pragma unroll
            for (int c=0;c<8;++c) acc[r][c]=0.f;

        #pragma unroll 4
        for (int d = 0; d < DIM; ++d) {
            float4 xv  = *(const float4*)&xsT[d][a*4];
            float4 t0v = *(const float4*)&tT[d][b*8];
            float4 t1v = *(const float4*)&tT[d][b*8+4];
            float xr[4] = {xv.x,xv.y,xv.z,xv.w};
            float tv[8] = {t0v.x,t0v.y,t0v.z,t0v.w,t1v.x,t1v.y,t1v.z,t1v.w};
            #pragma unroll
            for (int r=0;r<4;++r)
                #pragma unroll
                for (int c=0;c<8;++c) acc[r][c] = fmaf(xr[r], tv[c], acc[r][c]);
        }
        #pragma unroll
        for (int r=0;r<4;++r) {
            int row = rb + a*4 + r;
            float4 o0, o1;
            o0.x = tns[b*8+0] - 2.f*acc[r][0]; o0.y = tns[b*8+1] - 2.f*acc[r][1];
            o0.z = tns[b*8+2] - 2.f*acc[r][2]; o0.w = tns[b*8+3] - 2.f*acc[r][3];
            o1.x = tns[b*8+4] - 2.f*acc[r][4]; o1.y = tns[b*8+5] - 2.f*acc[r][5];
            o1.z = tns[b*8+6] - 2.f*acc[r][6]; o1.w = tns[b*8+7] - 2.f*acc[r][7];
            *(float4*)&sampleV[(size_t)row * NSAMP + t0 + b*8]     = o0;
            *(float4*)&sampleV[(size_t)row * NSAMP + t0 + b*8 + 4] = o1;
        }
    }
}

// ---------------- per-row threshold: 24th smallest sample value ----------------
__global__ __launch_bounds__(256) void kthresh(const float* __restrict__ sampleV,
                                               float* __restrict__ thrv)
{
    __shared__ float sv[NSAMP];
    __shared__ float red[8];
    const int row = blockIdx.x, tid = threadIdx.x;
    for (int s = tid; s < NSAMP; s += 256) sv[s] = sampleV[(size_t)row * NSAMP + s];
    __syncthreads();
    float lb = -1e30f;
    for (int it = 0; it < KSAMP; ++it) {
        float m = 1e30f;
        for (int s = tid; s < NSAMP; s += 256) {
            float v = sv[s];
            m = (v > lb && v < m) ? v : m;
        }
        #pragma unroll
        for (int o = 1; o < 64; o <<= 1) m = fminf(m, __shfl_xor(m, o));
        if ((tid & 63) == 0) red[tid >> 6] = m;
        __syncthreads();
        lb = fminf(fminf(red[0], red[1]), fminf(red[2], red[3]));
        __syncthreads();
    }
    if (tid == 0) thrv[row] = lb;
}

// ---------------- main distance pass v2: 64x128 tile, point-per-thread staging (bit-exact ----
// round-4 arithmetic: serial fmaf norm chain + serial fmaf dot), reg prefetch, LDS cand agg ----
__global__ __launch_bounds__(256, 3) void kdist2(const float* __restrict__ x,
                                                 const float* __restrict__ tX,
                                                 const float* __restrict__ thrv,
                                                 unsigned int* __restrict__ gcnt,
                                                 uint2* __restrict__ cand)
{
    __shared__ float tT[DIM][TN2];        // 32 KB  [dim][point]
    __shared__ float xsT[DIM][BM2];       // 16 KB  [dim][row]
    __shared__ float tns[TN2];            // 512 B
    __shared__ float thr_s[BM2];          // 256 B
    __shared__ uint2 cbuf[BM2][CBCAP];    // 3 KB
    __shared__ unsigned ccnt[BM2];        // 256 B

    const int tid = threadIdx.x;
    const int rb  = (blockIdx.x & 31) * BM2;
    const int ch  = blockIdx.x >> 5;
    const int p0c = ch * CH2;
    const int p1c = (p0c + CH2 < NTRAIN) ? p0c + CH2 : NTRAIN;
    const int nt  = (p1c - p0c + TN2 - 1) / TN2;

    const int a  = tid >> 5;          // row group (8 rows)
    const int b  = tid & 31;          // col group (4 cols)
    const int a8 = a * 8, b4 = b * 4;

    // ---- stage x rows transposed: thread (r=tid&63, d0=(tid>>6)*16) ----
    {
        int r = tid & 63, d0 = (tid >> 6) * 16;
        const float4* xp = (const float4*)(x + (size_t)(rb + r) * DIM + d0);
        #pragma unroll
        for (int q = 0; q < 4; ++q) {
            float4 v = xp[q];
            int d = d0 + 4 * q;
            xsT[d+0][r]=v.x; xsT[d+1][r]=v.y; xsT[d+2][r]=v.z; xsT[d+3][r]=v.w;
        }
    }
    if (tid < BM2) { thr_s[tid] = thrv[rb + tid]; ccnt[tid] = 0u; }

    float4 stg[16];   // one full point (64 dims), threads 0..127 only

    auto LOADT = [&](int t0) {        // issue global loads for point t0+tid
        if (tid < TN2) {
            int p  = t0 + tid;
            int pc = (p < NTRAIN) ? p : (NTRAIN - 1);
            const float4* tp = (const float4*)(tX + (size_t)pc * DIM);
            #pragma unroll
            for (int q = 0; q < 16; ++q) stg[q] = tp[q];
        }
    };
    auto WRITET = [&](int t0) {       // transpose-write + EXACT round-4 serial norm chain
        if (tid < TN2) {
            float nrm = 0.f;
            #pragma unroll
            for (int q = 0; q < 16; ++q) {
                float4 v = stg[q];
                int d = q * 4;
                tT[d+0][tid]=v.x; tT[d+1][tid]=v.y; tT[d+2][tid]=v.z; tT[d+3][tid]=v.w;
                nrm = fmaf(v.x,v.x,nrm); nrm = fmaf(v.y,v.y,nrm);
                nrm = fmaf(v.z,v.z,nrm); nrm = fmaf(v.w,v.w,nrm);
            }
            tns[tid] = (t0 + tid < p1c) ? nrm : 1e30f;
        }
    };
    auto FLUSH = [&]() {
        if (tid < BM2) {
            unsigned n = ccnt[tid];
            ccnt[tid] = 0u;
            if (n > CBCAP) n = CBCAP;
            if (n) {
                unsigned base = atomicAdd(&gcnt[rb + tid], n);
                for (unsigned k = 0; k < n; ++k)
                    if (base + k < CAP)
                        cand[(size_t)(rb + tid) * CAP + base + k] = cbuf[tid][k];
            }
        }
    };

    // ---- prologue: tile 0 ----
    LOADT(p0c);
    WRITET(p0c);
    __syncthreads();     // xsT, tT, tns, thr_s, ccnt all ready

    for (int t = 0; t < nt; ++t) {
        const int t0 = p0c + t * TN2;
        const bool more = (t + 1 < nt);
        if (more) LOADT(t0 + TN2);        // issue next tile's global loads early

        float acc[8][4];
        #pragma unroll
        for (int r = 0; r < 8; ++r)
            #pragma unroll
            for (int c = 0; c < 4; ++c) acc[r][c] = 0.f;

        #pragma unroll 4
        for (int d = 0; d < DIM; ++d) {
            float4 x0 = *(const float4*)&xsT[d][a8];
            float4 x1 = *(const float4*)&xsT[d][a8+4];
            float4 tv = *(const float4*)&tT[d][b4];
            float xr[8] = {x0.x,x0.y,x0.z,x0.w,x1.x,x1.y,x1.z,x1.w};
            float cv[4] = {tv.x,tv.y,tv.z,tv.w};
            #pragma unroll
            for (int r = 0; r < 8; ++r)
                #pragma unroll
                for (int c = 0; c < 4; ++c) acc[r][c] = fmaf(xr[r], cv[c], acc[r][c]);
        }

        // epilogue: threshold test + LDS-aggregated append
        {
            float4 tn = *(const float4*)&tns[b4];
            float tnv[4] = {tn.x, tn.y, tn.z, tn.w};
            #pragma unroll
            for (int rr = 0; rr < 8; ++rr) {
                const int lr = a8 + rr;
                const float th = thr_s[lr];
                #pragma unroll
                for (int cc = 0; cc < 4; ++cc) {
                    float v = tnv[cc] - 2.f * acc[rr][cc];
                    if (v <= th) {
                        unsigned bb  = __float_as_uint(v);
                        unsigned key = (bb >> 31) ? ~bb : (bb | 0x80000000u);
                        unsigned idx = (unsigned)(t0 + b4 + cc);
                        unsigned pos = atomicAdd(&ccnt[lr], 1u);
                        if (pos < CBCAP) {
                            cbuf[lr][pos] = make_uint2(key, idx);
                        } else {   // rare overflow: direct global append (still exact)
                            unsigned g = atomicAdd(&gcnt[rb + lr], 1u);
                            if (g < CAP) cand[(size_t)(rb + lr) * CAP + g] = make_uint2(key, idx);
                        }
                    }
                }
            }
        }
        __syncthreads();          // reads of tT/tns done; appends done
        FLUSH();                  // per-row global append + ccnt reset
        if (more) WRITET(t0 + TN2);
        __syncthreads();          // next tile staged; ccnt reset visible
    }
}

// ---------------- exact top-128 from candidates (binary search on key bits) ----------------
__global__ __launch_bounds__(256) void kselect(const unsigned int* __restrict__ gcnt,
                                               const uint2* __restrict__ cand,
                                               int* __restrict__ selIdx)
{
    __shared__ unsigned ku[CAP];
    __shared__ unsigned kid[CAP];
    __shared__ int redc[8];
    __shared__ int nsel;
    __shared__ int neq;
    __shared__ unsigned eqbuf[64];
    const int row = blockIdx.x, tid = threadIdx.x;
    int n = (int)gcnt[row]; if (n > CAP) n = CAP;
    for (int i = tid; i < n; i += 256) {
        uint2 e = cand[(size_t)row * CAP + i];
        ku[i] = e.x; kid[i] = e.y;
    }
    if (tid == 0) { nsel = 0; neq = 0; }
    __syncthreads();

    unsigned lo = 0u, hi = 0xFFFFFFFFu;
    for (int it = 0; it < 32; ++it) {
        unsigned mid = (unsigned)(((unsigned long long)lo + (unsigned long long)hi) >> 1);
        int c = 0;
        for (int i = tid; i < n; i += 256) c += (ku[i] <= mid) ? 1 : 0;
        #pragma unroll
        for (int o = 1; o < 64; o <<= 1) c += __shfl_xor(c, o);
        if ((tid & 63) == 0) redc[tid >> 6] = c;
        __syncthreads();
        int tot = redc[0] + redc[1] + redc[2] + redc[3];
        __syncthreads();
        if (tot >= KNN) hi = mid; else lo = mid + 1;
    }
    const unsigned ustar = hi;

    for (int i = tid; i < n; i += 256) {
        if (ku[i] < ustar) {
            int p = atomicAdd(&nsel, 1);
            if (p < KNN) selIdx[row * KNN + p] = (int)kid[i];
        } else if (ku[i] == ustar) {
            int p = atomicAdd(&neq, 1);
            if (p < 64) eqbuf[p] = kid[i];
        }
    }
    __syncthreads();
    if (tid == 0) {
        int cl = nsel; if (cl > KNN) cl = KNN;
        int need = KNN - cl;
        int ne = neq; if (ne > 64) ne = 64;
        // lowest-index tie-break to match lax.top_k stability
        for (int t = 0; t < need && t < ne; ++t) {
            int bi = t;
            for (int u = t + 1; u < ne; ++u) if (eqbuf[u] < eqbuf[bi]) bi = u;
            unsigned tmp = eqbuf[t]; eqbuf[t] = eqbuf[bi]; eqbuf[bi] = tmp;
            selIdx[row * KNN + cl + t] = (int)eqbuf[t];
        }
        int have = cl + (need < ne ? need : ne);
        for (int k2 = have; k2 < KNN; ++k2) selIdx[row * KNN + k2] = k2; // degenerate fallback
    }
}

// =================== ksolve3: blocked register-tile LU (panel=16), wave-factored panels ===========
// Thread (c=tid&127, h=tid>>7) owns rows [64h,64h+64) of column c in r[64] (static-indexed).
// Per panel: dump 16 cols -> LDS P; ONE WAVE factors the 128x16 panel in registers via __shfl
// (16 unrolled steps, rhs carried, no block barriers inside); then all threads apply the rank-16
// trailing update from broadcast LDS reads. Backsub: 16-lane shfl solve + parallel rank-16 updates.

#define PSTR 20                       // P row stride (floats): 80B, 16B-aligned
#define PIDX(row,col) ((row)*PSTR + (col))
#define UOFF 2560                     // Uc region offset in BUF (floats)

template<int LO>
__device__ __forceinline__ void dumpP(const float* r, float* BUF, int cB, int base) {
    #pragma unroll
    for (int i = LO; i < 64; ++i) BUF[PIDX(base + i, cB)] = r[i];
}

template<int LO>
__device__ __forceinline__ void loadP(float* r, const float* BUF, int cB, int base) {
    #pragma unroll
    for (int i = LO; i < 64; ++i) r[i] = BUF[PIDX(base + i, cB)];
}

template<int LO>
__device__ __forceinline__ void trail16(float* r, const float* u, const float* BUF, int base) {
    #pragma unroll
    for (int i = LO; i < 64; ++i) {
        const float* pr = &BUF[PIDX(base + i, 0)];
        float4 p0 = *(const float4*)(pr);
        float4 p1 = *(const float4*)(pr + 4);
        float4 p2 = *(const float4*)(pr + 8);
        float4 p3 = *(const float4*)(pr + 12);
        float s = r[i];
        s = fmaf(-p0.x, u[0],  s); s = fmaf(-p0.y, u[1],  s);
        s = fmaf(-p0.z, u[2],  s); s = fmaf(-p0.w, u[3],  s);
        s = fmaf(-p1.x, u[4],  s); s = fmaf(-p1.y, u[5],  s);
        s = fmaf(-p1.z, u[6],  s); s = fmaf(-p1.w, u[7],  s);
        s = fmaf(-p2.x, u[8],  s); s = fmaf(-p2.y, u[9],  s);
        s = fmaf(-p2.z, u[10], s); s = fmaf(-p2.w, u[11], s);
        s = fmaf(-p3.x, u[12], s); s = fmaf(-p3.y, u[13], s);
        s = fmaf(-p3.z, u[14], s); s = fmaf(-p3.w, u[15], s);
        r[i] = s;
    }
}

// h==hB trailing thread: triangular-update its 16 panel rows, publish U-seg, apply own trailing
template<int PO>
__device__ __forceinline__ void eqTrail(float* r, float* BUF, int jB, int base, int c) {
    #pragma unroll
    for (int a = 0; a < 15; ++a) {
        float va = r[PO + a];
        #pragma unroll
        for (int b = a + 1; b < 16; ++b)
            r[PO + b] = fmaf(-BUF[PIDX(jB + b, a)], va, r[PO + b]);
    }
    float u[16];
    #pragma unroll
    for (int jj = 0; jj < 16; ++jj) { u[jj] = r[PO + jj]; BUF[UOFF + c * PSTR + jj] = u[jj]; }
    trail16<PO + 16>(r, u, BUF, base);
}

template<int HI>
__device__ __forceinline__ void partW(const float* r, float* BUF, int base, int t, float wc) {
    #pragma unroll
    for (int i = 0; i < HI; ++i) BUF[UOFF + (base + i) * PSTR + t] = r[i] * wc;
}

template<int PO>
__device__ __forceinline__ void dumpDiag(const float* r, float* BUF, int cB) {
    #pragma unroll
    for (int rr = 0; rr < 16; ++rr) BUF[PIDX(rr, cB)] = r[PO + rr];
}

__global__ __launch_bounds__(256, 3) void ksolve3(const float* __restrict__ x,
                                                  const float* __restrict__ tX,
                                                  const float* __restrict__ ty,
                                                  const int* __restrict__ selIdx,
                                                  const float* __restrict__ pl,
                                                  const float* __restrict__ pa,
                                                  float* __restrict__ out)
{
    __shared__ float BUF[128 * 68];          // 34.8KB: XsR[c][d] (build) overlaid with P + Uc (solve)
    __shared__ float rhs[KNN], wv[KNN], c0v[KNN], nyv[KNN], nrmL[KNN];
    __shared__ float xq[DIM];
    __shared__ float nrm2f[2][KNN];
    __shared__ int   sel[KNN];
    __shared__ float red[8];

    const int tid = threadIdx.x;
    const int row = blockIdx.x;
    const int c = tid & 127;
    const int h = tid >> 7;
    const int base = 64 * h;
    const float ll = pl[0], aamp = pa[0];
    const float in2 = 1.0f / (2.0f * ll * ll);

    if (tid < KNN) sel[tid] = selIdx[row * KNN + tid];
    if (tid < DIM) xq[tid] = x[(size_t)row * DIM + tid];
    __syncthreads();

    // ---- stage neighbor rows (row-major) + partial norms ----
    {
        const float* tp = tX + (size_t)sel[c] * DIM + 32 * h;
        float pn = 0.f;
        #pragma unroll
        for (int q = 0; q < 8; ++q) {
            float4 v = *(const float4*)(tp + 4 * q);
            *(float4*)&BUF[c * 68 + 32 * h + 4 * q] = v;
            pn = fmaf(v.x, v.x, fmaf(v.y, v.y, fmaf(v.z, v.z, fmaf(v.w, v.w, pn))));
        }
        nrm2f[h][c] = pn;
        if (h == 0) nyv[c] = ty[sel[c]];
    }
    __syncthreads();

    // ---- per-column: norms + crossCov (rhs) ----
    if (h == 0) {
        float nn = nrm2f[0][c] + nrm2f[1][c];
        nrmL[c] = nn;
        float xd = 0.f, xn = 0.f;
        for (int d = 0; d < DIM; ++d) {
            float xv = xq[d];
            float t = BUF[c * 68 + d];
            xd = fmaf(xv, t, xd);
            xn = fmaf(xv, xv, xn);
        }
        float d2 = fmaxf(xn + nn - 2.f * xd, 0.f);
        float cv = aamp * __expf(-d2 * in2);
        c0v[c] = cv;
        rhs[c] = cv;
    }
    __syncthreads();

    // ---- Gram into registers ----
    float r[64];
    #pragma unroll
    for (int i = 0; i < 64; ++i) r[i] = 0.f;
    for (int q4 = 0; q4 < 4; ++q4) {
        float od[16];
        #pragma unroll
        for (int q = 0; q < 4; ++q)
            *(float4*)&od[4 * q] = *(const float4*)&BUF[c * 68 + 16 * q4 + 4 * q];
        #pragma unroll
        for (int i = 0; i < 64; ++i) {
            const float* br = &BUF[(base + i) * 68 + 16 * q4];
            float4 b0 = *(const float4*)(br);
            float4 b1 = *(const float4*)(br + 4);
            float4 b2 = *(const float4*)(br + 8);
            float4 b3 = *(const float4*)(br + 12);
            float s = r[i];
            s = fmaf(b0.x, od[0],  s); s = fmaf(b0.y, od[1],  s);
            s = fmaf(b0.z, od[2],  s); s = fmaf(b0.w, od[3],  s);
            s = fmaf(b1.x, od[4],  s); s = fmaf(b1.y, od[5],  s);
            s = fmaf(b1.z, od[6],  s); s = fmaf(b1.w, od[7],  s);
            s = fmaf(b2.x, od[8],  s); s = fmaf(b2.y, od[9],  s);
            s = fmaf(b2.z, od[10], s); s = fmaf(b2.w, od[11], s);
            s = fmaf(b3.x, od[12], s); s = fmaf(b3.y, od[13], s);
            s = fmaf(b3.z, od[14], s); s = fmaf(b3.w, od[15], s);
            r[i] = s;
        }
    }
    // ---- transform Gram -> kernel matrix (in registers) ----
    {
        const float ncl = nrmL[c];
        #pragma unroll
        for (int i = 0; i < 64; ++i) {
            float d2 = fmaxf(nrmL[base + i] + ncl - 2.f * r[i], 0.f);
            r[i] = aamp * __expf(-d2 * in2);
        }
    }
    __syncthreads();   // hand BUF over from XsR to P/Uc

    // ================= forward: blocked LU, 8 panels =================
    for (int kb = 0; kb < 8; ++kb) {
        const int jB = 16 * kb;
        const int po = jB - base;                 // panel offset in local row coords
        const bool inB = (c >= jB) && (c < jB + 16);
        const bool trC = (c > jB + 15);

        // --- A: dump panel columns to P ---
        if (inB) {
            const int cB = c - jB;
            if (po < 0)            dumpP<0>(r, BUF, cB, base);
            else if (po == 0)      dumpP<0>(r, BUF, cB, base);
            else if (po == 16)     dumpP<16>(r, BUF, cB, base);
            else if (po == 32)     dumpP<32>(r, BUF, cB, base);
            else if (po == 48)     dumpP<48>(r, BUF, cB, base);
        }
        __syncthreads();

        // --- B: wave 0 factors the 128x16 panel + rhs in registers via shfl ---
        if (tid < 64) {
            const int l = tid;
            const int ga = jB + l, gb = jB + 64 + l;
            const bool va = ga < 128, vb = gb < 128;
            float ra[16], rb[16], rha = 0.f, rhb = 0.f;
            if (va) {
                #pragma unroll
                for (int q = 0; q < 4; ++q) *(float4*)&ra[4*q] = *(const float4*)&BUF[PIDX(ga, 4*q)];
                rha = rhs[ga];
            }
            if (vb) {
                #pragma unroll
                for (int q = 0; q < 4; ++q) *(float4*)&rb[4*q] = *(const float4*)&BUF[PIDX(gb, 4*q)];
                rhb = rhs[gb];
            }
            #pragma unroll
            for (int jj = 0; jj < 16; ++jj) {
                float pv[16];
                #pragma unroll
                for (int q = 0; q < 16; ++q) pv[q] = __shfl(ra[q], jj);
                float pvr = __shfl(rha, jj);
                const float rc = 1.0f / pv[jj];
                if (va && l > jj) {
                    float m = ra[jj] * rc; ra[jj] = m;
                    #pragma unroll
                    for (int cc = jj + 1; cc < 16; ++cc) ra[cc] = fmaf(-m, pv[cc], ra[cc]);
                    rha = fmaf(-m, pvr, rha);
                }
                if (vb) {
                    float m = rb[jj] * rc; rb[jj] = m;
                    #pragma unroll
                    for (int cc = jj + 1; cc < 16; ++cc) rb[cc] = fmaf(-m, pv[cc], rb[cc]);
                    rhb = fmaf(-m, pvr, rhb);
                }
            }
            if (va) {
                #pragma unroll
                for (int q = 0; q < 4; ++q) *(float4*)&BUF[PIDX(ga, 4*q)] = *(const float4*)&ra[4*q];
                rhs[ga] = rha;
            }
            if (vb) {
                #pragma unroll
                for (int q = 0; q < 4; ++q) *(float4*)&BUF[PIDX(gb, 4*q)] = *(const float4*)&rb[4*q];
                rhs[gb] = rhb;
            }
        }
        __syncthreads();

        // --- C: readback for panel columns; h==hB trailing: tri-update + publish U-seg + own trail ---
        if (po >= 0 && po < 64) {                 // h == hB
            if (inB) {
                const int cB = c - jB;
                if (po == 0)       loadP<0>(r, BUF, cB, base);
                else if (po == 16) loadP<16>(r, BUF, cB, base);
                else if (po == 32) loadP<32>(r, BUF, cB, base);
                else               loadP<48>(r, BUF, cB, base);
            } else if (trC) {
                if (po == 0)       eqTrail<0>(r, BUF, jB, base, c);
                else if (po == 16) eqTrail<16>(r, BUF, jB, base, c);
                else if (po == 32) eqTrail<32>(r, BUF, jB, base, c);
                else               eqTrail<48>(r, BUF, jB, base, c);
            }
        } else if (po < 0) {                      // h > hB
            if (inB) loadP<0>(r, BUF, c - jB, base);
        }
        __syncthreads();

        // --- D: h>hB trailing threads apply rank-16 update with U-seg from Uc ---
        if (po < 0 && trC) {
            float u[16];
            #pragma unroll
            for (int q = 0; q < 4; ++q)
                *(float4*)&u[4*q] = *(const float4*)&BUF[UOFF + c * PSTR + 4*q];
            trail16<0>(r, u, BUF, base);
        }
        __syncthreads();
    }

    // ================= backsub: 8 blocks, top-down =================
    for (int kb = 7; kb >= 0; --kb) {
        const int jB = 16 * kb;
        const int po = jB - base;
        const bool inB = (c >= jB) && (c < jB + 16);

        // --- A: diag-block dump (h==hB, c in B) ---
        if (inB && po >= 0 && po < 64) {
            const int cB = c - jB;
            if (po == 0)       dumpDiag<0>(r, BUF, cB);
            else if (po == 16) dumpDiag<16>(r, BUF, cB);
            else if (po == 32) dumpDiag<32>(r, BUF, cB);
            else               dumpDiag<48>(r, BUF, cB);
        }
        __syncthreads();

        // --- B: 16-lane shfl solve of upper-triangular 16x16 ---
        if (tid < 16) {
            float rl = rhs[jB + tid];
            #pragma unroll
            for (int t = 15; t >= 0; --t) {
                float rj = __shfl(rl, t);
                float wj = rj / BUF[PIDX(t, t)];
                if (tid == t) wv[jB + t] = wj;
                if (tid < t) rl = fmaf(-BUF[PIDX(tid, t)], wj, rl);
            }
        }
        __syncthreads();

        if (kb > 0) {
            // --- C: partial products U[row][c]*w_c into Uc slots ---
            if (inB) {
                const float wc = wv[c];
                const int t = c - jB;
                if (po >= 64)      partW<64>(r, BUF, base, t, wc);   // h < hB: all 64 rows < jB
                else if (po == 16) partW<16>(r, BUF, base, t, wc);
                else if (po == 32) partW<32>(r, BUF, base, t, wc);
                else if (po == 48) partW<48>(r, BUF, base, t, wc);
                // po == 0: no rows above panel in this half
            }
            __syncthreads();
            // --- D: reduce 16 partials per row into rhs ---
            if (tid < jB) {
                const float* up = &BUF[UOFF + tid * PSTR];
                float4 v0 = *(const float4*)(up);
                float4 v1 = *(const float4*)(up + 4);
                float4 v2 = *(const float4*)(up + 8);
                float4 v3 = *(const float4*)(up + 12);
                float s = v0.x + v0.y + v0.z + v0.w + v1.x + v1.y + v1.z + v1.w
                        + v2.x + v2.y + v2.z + v2.w + v3.x + v3.y + v3.z + v3.w;
                rhs[tid] -= s;
            }
            __syncthreads();
        }
    }
    __syncthreads();

    // ---- outputs: y = w.ny ; yVar = a - w.c ----
    float py = 0.f, pq = 0.f;
    if (tid < KNN) {
        float w = wv[tid];
        py = w * nyv[tid];
        pq = w * c0v[tid];
    }
    #pragma unroll
    for (int o = 1; o < 64; o <<= 1) { py += __shfl_xor(py, o); pq += __shfl_xor(pq, o); }
    if ((tid & 63) == 0) { red[tid >> 6] = py; red[4 + (tid >> 6)] = pq; }
    __syncthreads();
    if (tid == 0) {
        float y = red[0] + red[1] + red[2] + red[3];
        float q = red[4] + red[5] + red[6] + red[7];
        out[row]         = y;
        out[BATCH + row] = aamp - q;
    }
}

extern "C" void kernel_launch(void* const* d_in, const int* in_sizes, int n_in,
                              void* d_out, int out_size, void* d_ws, size_t ws_size,
                              hipStream_t stream)
{
    const float* x  = (const float*)d_in[0];
    const float* tX = (const float*)d_in[1];
    const float* ty = (const float*)d_in[2];
    const float* pl = (const float*)d_in[3];
    const float* pa = (const float*)d_in[4];
    float* out = (float*)d_out;
    char* ws = (char*)d_ws;

    float*        thrv    = (float*)(ws + OFF_THR);
    unsigned int* gcnt    = (unsigned int*)(ws + OFF_CNT);
    int*          sel     = (int*)(ws + OFF_SEL);
    uint2*        cand    = (uint2*)(ws + OFF_CAND);
    float*        sampleV = (float*)(ws + OFF_CAND);  // aliased: consumed before cand is written

    hipMemsetAsync(gcnt, 0, BATCH * sizeof(unsigned int), stream);
    ksample<<<BATCH / BM, 256, 0, stream>>>(x, tX, sampleV);
    kthresh<<<BATCH, 256, 0, stream>>>(sampleV, thrv);
    kdist2<<<32 * NCH2, 256, 0, stream>>>(x, tX, thrv, gcnt, cand);
    kselect<<<BATCH, 256, 0, stream>>>(gcnt, cand, sel);
    ksolve3<<<BATCH, 256, 0, stream>>>(x, tX, ty, sel, pl, pa, out);
}